// Round 6
// baseline (9101.492 us; speedup 1.0000x reference)
//
#include <hip/hip_runtime.h>
#include <stdint.h>

#define BB 512
#define TT 512
#define FF 128
#define UU 256

typedef float f32x4 __attribute__((ext_vector_type(4)));
typedef short short8 __attribute__((ext_vector_type(8)));
typedef float float4v __attribute__((ext_vector_type(4)));
typedef unsigned short ushort4v __attribute__((ext_vector_type(4)));

__device__ __forceinline__ unsigned short f2bf(float f) {
  union { float f; uint32_t u; } v; v.f = f;
  uint32_t u = v.u;
  u += 0x7fffu + ((u >> 16) & 1u);
  return (unsigned short)(u >> 16);
}
__device__ __forceinline__ float fast_rcp(float x) { return __builtin_amdgcn_rcpf(x); }
__device__ __forceinline__ float sigmoidf_(float x) { return fast_rcp(1.f + __expf(-x)); }
__device__ __forceinline__ float tanhf_(float x) { return 1.f - 2.f * fast_rcp(1.f + __expf(2.f * x)); }

// ---- prep: W^T combined [1024 cols][384 k] bf16, Wo^T [32][256] bf16 --------------------
__global__ void prep_w(const float* __restrict__ Wx, const float* __restrict__ Wh,
                       const float* __restrict__ Wo,
                       unsigned short* __restrict__ Wt, unsigned short* __restrict__ Wot) {
  int bidx = blockIdx.x;
  int tid = threadIdx.x; // 384
  if (bidx < 1024) {
    int n = bidx, k = tid;
    float v = (k < FF) ? Wx[(size_t)k * 1024 + n] : Wh[(size_t)(k - FF) * 1024 + n];
    Wt[(size_t)n * 384 + k] = f2bf(v);
  } else {
    for (int i = tid; i < 32 * 256; i += 384) {
      int o = i >> 8, u = i & 255;
      Wot[o * 256 + u] = f2bf(Wo[(size_t)u * 32 + o]);
    }
  }
}

// ---- x f32 -> bf16 ----------------------------------------------------------------------
__global__ void conv_x(const float* __restrict__ xf, unsigned short* __restrict__ xb) {
  size_t i = (size_t)blockIdx.x * 1024 + (size_t)threadIdx.x * 4;
  float4v v = *(const float4v*)(xf + i);
  ushort4v o;
  o.x = f2bf(v.x); o.y = f2bf(v.y); o.z = f2bf(v.z); o.w = f2bf(v.w);
  *(ushort4v*)(xb + i) = o;
}

__device__ __forceinline__ short8 load_xfrag(const unsigned short* p) {
  return *(const short8*)p;
}
__device__ __forceinline__ short8 load_xfrag(const float* p) {
  float4v lo = *(const float4v*)p;
  float4v hi = *(const float4v*)(p + 4);
  union { short8 v; unsigned short s[8]; } a;
  a.s[0] = f2bf(lo.x); a.s[1] = f2bf(lo.y); a.s[2] = f2bf(lo.z); a.s[3] = f2bf(lo.w);
  a.s[4] = f2bf(hi.x); a.s[5] = f2bf(hi.y); a.s[6] = f2bf(hi.z); a.s[7] = f2bf(hi.w);
  return a.v;
}

// ---- recurrent core: ONE block per m-tile (16 batch rows), all 256 units, LDS-only ------
// 1024 threads = 16 waves. Wave w owns units w*16..w*16+15, all 4 gates.
// LDS: h double buffer [2][16 rows][256 units] bf16, XOR-swizzled, 16 KB.
template <typename XT>
__global__ void __launch_bounds__(1024, 1)
lstm_main6(const XT* __restrict__ x, const unsigned short* __restrict__ Wt,
           const float* __restrict__ bvec, unsigned short* __restrict__ h_hist) {
  __shared__ __align__(16) char lds[16384];

  const int bid = blockIdx.x;       // 0..31, m-tile
  const int tid = threadIdx.x;
  const int w = tid >> 6, l = tid & 63;
  const int lr = l & 15, lhi = l >> 4;
  const int b0 = bid * 16;
  const int uloc = w * 16 + lr;     // unit col in [0,256)

  // Bf[gate][kfrag]: kfrag 0..3 = x (F=128), 4..11 = h (U=256). 48 short8 = 192 regs.
  short8 Bf[4][12];
#pragma unroll
  for (int g = 0; g < 4; ++g) {
    const unsigned short* wp = Wt + (size_t)(g * 256 + uloc) * 384 + 8 * lhi;
#pragma unroll
    for (int k = 0; k < 12; ++k) Bf[g][k] = *(const short8*)(wp + k * 32);
  }
  float bias[4];
#pragma unroll
  for (int g = 0; g < 4; ++g) bias[g] = bvec[g * 256 + uloc];
  float cst[4] = {0.f, 0.f, 0.f, 0.f};

  // prologue x prefetch (t=0)
  short8 xa[4];
  {
    const XT* xp = x + ((size_t)(b0 + lr) * TT + 0) * FF + 8 * lhi;
#pragma unroll
    for (int kk = 0; kk < 4; ++kk) xa[kk] = load_xfrag(xp + kk * 32);
  }

#pragma unroll 1
  for (int t = 0; t < TT; ++t) {
    const int cur = t & 1, nxt = cur ^ 1;

    f32x4 acc[4];
#pragma unroll
    for (int g = 0; g < 4; ++g) { f32x4 a4 = {bias[g], bias[g], bias[g], bias[g]}; acc[g] = a4; }

    if (t > 0) {
      // h(t) from LDS: 8 kfrags covering all 256 units
      short8 ha[8];
#pragma unroll
      for (int ko = 0; ko < 8; ++ko) {
        const int byte = cur * 8192 + lr * 512 + ((ko * 64 + lhi * 16) ^ ((lr & 7) << 4));
        ha[ko] = *(const short8*)(lds + byte);
      }
#pragma unroll
      for (int ko = 0; ko < 8; ++ko)
#pragma unroll
        for (int g = 0; g < 4; ++g)
          acc[g] = __builtin_amdgcn_mfma_f32_16x16x32_bf16(ha[ko], Bf[g][4 + ko], acc[g], 0, 0, 0);
    }

    // x-part MFMAs (xa prefetched)
#pragma unroll
    for (int kk = 0; kk < 4; ++kk)
#pragma unroll
      for (int g = 0; g < 4; ++g)
        acc[g] = __builtin_amdgcn_mfma_f32_16x16x32_bf16(xa[kk], Bf[g][kk], acc[g], 0, 0, 0);

    // x prefetch for t+1 (overlaps gates/stores)
    {
      const int tn = (t + 1 < TT) ? t + 1 : t;
      const XT* xp = x + ((size_t)(b0 + lr) * TT + tn) * FF + 8 * lhi;
#pragma unroll
      for (int kk = 0; kk < 4; ++kk) xa[kk] = load_xfrag(xp + kk * 32);
    }

    // gates: thread holds i,f,g,o for rows b0+4*lhi+r, unit uloc
    unsigned short hs[4];
#pragma unroll
    for (int r = 0; r < 4; ++r) {
      float zi = acc[0][r], zf = acc[1][r], zg = acc[2][r], zo = acc[3][r];
      float si = sigmoidf_(zi), sf = sigmoidf_(zf), so = sigmoidf_(zo);
      float tg = tanhf_(zg);
      float cn = sf * cst[r] + si * tg;
      cst[r] = cn;
      hs[r] = f2bf(so * tanhf_(cn));
    }

    // write h(t+1): LDS (swizzled) + h_hist (plain cached; y_gemm reads after kernel end)
    unsigned short* hw = h_hist + (size_t)(t + 1) * (BB * UU) + uloc;
#pragma unroll
    for (int r = 0; r < 4; ++r) {
      const int row = 4 * lhi + r;
      const int byte = nxt * 8192 + row * 512 + ((uloc * 2) ^ ((row & 7) << 4));
      *(unsigned short*)(lds + byte) = hs[r];
      hw[(size_t)(b0 + row) * UU] = hs[r];
    }

    __syncthreads();
  }
}

// ---- y = h @ Wo + bo --------------------------------------------------------------------
__global__ void __launch_bounds__(256)
y_gemm(const unsigned short* __restrict__ h_hist, const unsigned short* __restrict__ Wot,
       const float* __restrict__ bo, float* __restrict__ out) {
  int gw = (int)((blockIdx.x * 256 + threadIdx.x) >> 6);
  int l = threadIdx.x & 63;
  int lr = l & 15, lhi = l >> 4;
  int b = gw >> 5;
  int t0 = (gw & 31) * 16;

  short8 Wf[2][8];
#pragma unroll
  for (int n = 0; n < 2; ++n) {
    const unsigned short* wp = Wot + (n * 16 + lr) * 256 + 8 * lhi;
#pragma unroll
    for (int kk = 0; kk < 8; ++kk) Wf[n][kk] = *(const short8*)(wp + kk * 32);
  }
  f32x4 acc[2];
#pragma unroll
  for (int n = 0; n < 2; ++n) {
    float bb = bo[n * 16 + lr];
    f32x4 a4 = {bb, bb, bb, bb};
    acc[n] = a4;
  }
  const unsigned short* hp =
      h_hist + ((size_t)(t0 + lr + 1) * BB + b) * UU + 8 * lhi;
#pragma unroll
  for (int kk = 0; kk < 8; ++kk) {
    short8 a = *(const short8*)(hp + kk * 32);
#pragma unroll
    for (int n = 0; n < 2; ++n)
      acc[n] = __builtin_amdgcn_mfma_f32_16x16x32_bf16(a, Wf[n][kk], acc[n], 0, 0, 0);
  }
#pragma unroll
  for (int n = 0; n < 2; ++n) {
    int o = n * 16 + lr;
#pragma unroll
    for (int r = 0; r < 4; ++r) {
      int t = t0 + 4 * lhi + r;
      out[((size_t)b * TT + t) * 32 + o] = acc[n][r];
    }
  }
}

extern "C" void kernel_launch(void* const* d_in, const int* in_sizes, int n_in,
                              void* d_out, int out_size, void* d_ws, size_t ws_size,
                              hipStream_t stream) {
  const float* x  = (const float*)d_in[0];
  const float* Wx = (const float*)d_in[1];
  const float* Wh = (const float*)d_in[2];
  const float* bv = (const float*)d_in[3];
  const float* Wo = (const float*)d_in[4];
  const float* bo = (const float*)d_in[5];

  char* ws = (char*)d_ws;
  size_t off = 0;
  unsigned short* h_hist = (unsigned short*)(ws + off); off += (size_t)513 * BB * UU * 2; // 134.5 MB
  unsigned short* Wt384  = (unsigned short*)(ws + off); off += (size_t)1024 * 384 * 2;
  unsigned short* Wot    = (unsigned short*)(ws + off); off += (size_t)32 * 256 * 2;
  off = (off + 255) & ~(size_t)255;
  unsigned short* xb = (unsigned short*)(ws + off);
  const size_t need_xb = off + (size_t)BB * TT * FF * 2;  // ~202 MB total

  prep_w<<<1025, 384, 0, stream>>>(Wx, Wh, Wo, Wt384, Wot);
  if (ws_size >= need_xb) {
    conv_x<<<32768, 256, 0, stream>>>(x, xb);
    lstm_main6<unsigned short><<<32, 1024, 0, stream>>>(xb, Wt384, bv, h_hist);
  } else {
    lstm_main6<float><<<32, 1024, 0, stream>>>(x, Wt384, bv, h_hist);
  }
  y_gemm<<<4096, 256, 0, stream>>>(h_hist, Wot, bo, (float*)d_out);
}

// Round 7
// 1799.290 us; speedup vs baseline: 5.0584x; 5.0584x over previous
//
#include <hip/hip_runtime.h>
#include <stdint.h>

#define BB 512
#define TT 512
#define FF 128
#define UU 256

typedef float f32x4 __attribute__((ext_vector_type(4)));
typedef short short8 __attribute__((ext_vector_type(8)));
typedef int int4v __attribute__((ext_vector_type(4)));
typedef float float4v __attribute__((ext_vector_type(4)));
typedef unsigned short ushort4v __attribute__((ext_vector_type(4)));

__device__ __forceinline__ unsigned short f2bf(float f) {
  union { float f; uint32_t u; } v; v.f = f;
  uint32_t u = v.u;
  u += 0x7fffu + ((u >> 16) & 1u);
  return (unsigned short)(u >> 16);
}
__device__ __forceinline__ float fast_rcp(float x) { return __builtin_amdgcn_rcpf(x); }
__device__ __forceinline__ float sigmoidf_(float x) { return fast_rcp(1.f + __expf(-x)); }
__device__ __forceinline__ float tanhf_(float x) { return 1.f - 2.f * fast_rcp(1.f + __expf(2.f * x)); }

// ---- prep: W^T combined [1024 cols][384 k] bf16, Wo^T [32][256] bf16, zero flags -------
__global__ void prep_w(const float* __restrict__ Wx, const float* __restrict__ Wh,
                       const float* __restrict__ Wo,
                       unsigned short* __restrict__ Wt, unsigned short* __restrict__ Wot,
                       int* __restrict__ flags) {
  int bidx = blockIdx.x;
  int tid = threadIdx.x; // 384
  if (bidx < 1024) {
    int n = bidx, k = tid;
    float v = (k < FF) ? Wx[(size_t)k * 1024 + n] : Wh[(size_t)(k - FF) * 1024 + n];
    Wt[(size_t)n * 384 + k] = f2bf(v);
  } else if (bidx == 1024) {
    for (int i = tid; i < 32 * 256; i += 384) {
      int o = i >> 8, u = i & 255;
      Wot[o * 256 + u] = f2bf(Wo[(size_t)u * 32 + o]);
    }
  } else {
    for (int i = tid; i < 64 * 32; i += 384)
      __hip_atomic_store(&flags[i], 0, __ATOMIC_RELAXED, __HIP_MEMORY_SCOPE_SYSTEM);
  }
}

// ---- x f32 -> bf16 ----------------------------------------------------------------------
__global__ void conv_x(const float* __restrict__ xf, unsigned short* __restrict__ xb) {
  size_t i = (size_t)blockIdx.x * 1024 + (size_t)threadIdx.x * 4;
  float4v v = *(const float4v*)(xf + i);
  ushort4v o;
  o.x = f2bf(v.x); o.y = f2bf(v.y); o.z = f2bf(v.z); o.w = f2bf(v.w);
  *(ushort4v*)(xb + i) = o;
}

__device__ __forceinline__ short8 load_xfrag(const unsigned short* p) {
  return *(const short8*)p;
}
__device__ __forceinline__ short8 load_xfrag(const float* p) {
  float4v lo = *(const float4v*)p;
  float4v hi = *(const float4v*)(p + 4);
  union { short8 v; unsigned short s[8]; } a;
  a.s[0] = f2bf(lo.x); a.s[1] = f2bf(lo.y); a.s[2] = f2bf(lo.z); a.s[3] = f2bf(lo.w);
  a.s[4] = f2bf(hi.x); a.s[5] = f2bf(hi.y); a.s[6] = f2bf(hi.z); a.s[7] = f2bf(hi.w);
  return a.v;
}

// coherent (MALL) 16B x4 load for partner h
__device__ __forceinline__ void load4_coh(const unsigned short* p,
                                          short8& q0, short8& q1, short8& q2, short8& q3) {
  int4v a0, a1, a2, a3;
  asm volatile(
      "global_load_dwordx4 %0, %4, off sc0 sc1\n\t"
      "global_load_dwordx4 %1, %4, off offset:64 sc0 sc1\n\t"
      "global_load_dwordx4 %2, %4, off offset:128 sc0 sc1\n\t"
      "global_load_dwordx4 %3, %4, off offset:192 sc0 sc1\n\t"
      "s_waitcnt vmcnt(0)"
      : "=&v"(a0), "=&v"(a1), "=&v"(a2), "=&v"(a3) : "v"(p) : "memory");
  __builtin_amdgcn_sched_barrier(0);  // rule #18
  q0 = __builtin_bit_cast(short8, a0);
  q1 = __builtin_bit_cast(short8, a1);
  q2 = __builtin_bit_cast(short8, a2);
  q3 = __builtin_bit_cast(short8, a3);
}
__device__ __forceinline__ void store_coh_u16(unsigned short* p, unsigned short v) {
  asm volatile("global_store_short %0, %1, off sc0 sc1" :: "v"(p), "v"((uint32_t)v) : "memory");
}

// ---- recurrent core: 2 CUs per m-tile; Wh in regs (128), Wx in LDS (128KB) --------------
// LDS: [0..131071] Wx frags: ((w*16 + g*4 + kk)*64 + l)*16 ; [131072..139263] h dbuf.
template <int HALF, typename XT>
__device__ __forceinline__ void lstm_core(const XT* __restrict__ x,
                                          const unsigned short* __restrict__ Wt,
                                          const float* __restrict__ bvec,
                                          unsigned short* __restrict__ h_hist,
                                          int* flags, int bid, char* lds) {
  const int mt = bid & 31;
  const int partner = bid ^ 32;
  const int tid = threadIdx.x;
  const int w = tid >> 6, l = tid & 63;
  const int lr = l & 15, lhi = l >> 4;
  const int b0 = mt * 16;
  const int uloc = HALF * 128 + w * 16 + lr;  // global unit col in [0,256)
  char* hlds = lds + 131072;

  // stage Wx fragments (this wave's 16) into LDS — identity map, read back verbatim
#pragma unroll
  for (int g = 0; g < 4; ++g)
#pragma unroll
    for (int kk = 0; kk < 4; ++kk) {
      const unsigned short* wp = Wt + (size_t)(g * 256 + uloc) * 384 + kk * 32 + 8 * lhi;
      *(short8*)(lds + ((size_t)((w * 16 + g * 4 + kk) * 64 + l)) * 16) = *(const short8*)wp;
    }

  // Wh fragments in registers: Bh[gate][kf], kf 0..7 over all 256 units (k of h-GEMM)
  short8 Bh[4][8];
#pragma unroll
  for (int g = 0; g < 4; ++g) {
    const unsigned short* wp = Wt + (size_t)(g * 256 + uloc) * 384 + FF + 8 * lhi;
#pragma unroll
    for (int kf = 0; kf < 8; ++kf) Bh[g][kf] = *(const short8*)(wp + kf * 32);
  }
  float bias[4];
#pragma unroll
  for (int g = 0; g < 4; ++g) bias[g] = bvec[g * 256 + uloc];
  float cst[4] = {0.f, 0.f, 0.f, 0.f};

  constexpr int kf_own = HALF * 4;
  constexpr int kf_par = (1 - HALF) * 4;
  constexpr int kh_par = (1 - HALF) * 128;

  const int* fp = flags + partner * 32;

  // prologue x prefetch (t=0)
  short8 xa[4];
  {
    const XT* xp = x + ((size_t)(b0 + lr) * TT + 0) * FF + 8 * lhi;
#pragma unroll
    for (int kk = 0; kk < 4; ++kk) xa[kk] = load_xfrag(xp + kk * 32);
  }
  __syncthreads();  // Wx staging complete

#pragma unroll 1
  for (int t = 0; t < TT; ++t) {
    const int cur = t & 1, nxt = cur ^ 1;

    f32x4 acc[4];
#pragma unroll
    for (int g = 0; g < 4; ++g) { f32x4 a4 = {bias[g], bias[g], bias[g], bias[g]}; acc[g] = a4; }

    if (t > 0) {
      // own-half h(t) from LDS dbuf, 4 k-frags
      short8 ho[4];
#pragma unroll
      for (int ko = 0; ko < 4; ++ko) {
        const int byte = cur * 4096 + lr * 256 + ((ko * 64 + lhi * 16) ^ ((lr & 7) << 4));
        ho[ko] = *(const short8*)(hlds + byte);
      }
#pragma unroll
      for (int ko = 0; ko < 4; ++ko)
#pragma unroll
        for (int g = 0; g < 4; ++g)
          acc[g] = __builtin_amdgcn_mfma_f32_16x16x32_bf16(ho[ko], Bh[g][kf_own + ko], acc[g], 0, 0, 0);
    }

    // x-part: B-frags streamed from LDS
#pragma unroll
    for (int kk = 0; kk < 4; ++kk) {
      short8 bx[4];
#pragma unroll
      for (int g = 0; g < 4; ++g)
        bx[g] = *(const short8*)(lds + ((size_t)((w * 16 + g * 4 + kk) * 64 + l)) * 16);
#pragma unroll
      for (int g = 0; g < 4; ++g)
        acc[g] = __builtin_amdgcn_mfma_f32_16x16x32_bf16(xa[kk], bx[g], acc[g], 0, 0, 0);
    }

    // x prefetch for t+1 (overlaps the poll below)
    {
      const int tn = (t + 1 < TT) ? t + 1 : t;
      const XT* xp = x + ((size_t)(b0 + lr) * TT + tn) * FF + 8 * lhi;
#pragma unroll
      for (int kk = 0; kk < 4; ++kk) xa[kk] = load_xfrag(xp + kk * 32);
    }

    if (t > 0) {
      // wait for partner's step-t publish (flag at MALL)
      int fv;
      do {
        asm volatile("global_load_dword %0, %1, off sc0 sc1\n\ts_waitcnt vmcnt(0)"
                     : "=v"(fv) : "v"(fp) : "memory");
      } while (fv < t);
      __builtin_amdgcn_sched_barrier(0);

      const unsigned short* hpp =
          h_hist + (size_t)t * (BB * UU) + (size_t)(b0 + lr) * UU + 8 * lhi + kh_par;
      short8 hq0, hq1, hq2, hq3;
      load4_coh(hpp, hq0, hq1, hq2, hq3);
#pragma unroll
      for (int g = 0; g < 4; ++g) acc[g] = __builtin_amdgcn_mfma_f32_16x16x32_bf16(hq0, Bh[g][kf_par + 0], acc[g], 0, 0, 0);
#pragma unroll
      for (int g = 0; g < 4; ++g) acc[g] = __builtin_amdgcn_mfma_f32_16x16x32_bf16(hq1, Bh[g][kf_par + 1], acc[g], 0, 0, 0);
#pragma unroll
      for (int g = 0; g < 4; ++g) acc[g] = __builtin_amdgcn_mfma_f32_16x16x32_bf16(hq2, Bh[g][kf_par + 2], acc[g], 0, 0, 0);
#pragma unroll
      for (int g = 0; g < 4; ++g) acc[g] = __builtin_amdgcn_mfma_f32_16x16x32_bf16(hq3, Bh[g][kf_par + 3], acc[g], 0, 0, 0);
    }

    // gates: thread holds i,f,g,o for rows b0+4*lhi+r, unit uloc
    unsigned short hs[4];
#pragma unroll
    for (int r = 0; r < 4; ++r) {
      float zi = acc[0][r], zf = acc[1][r], zg = acc[2][r], zo = acc[3][r];
      float si = sigmoidf_(zi), sf = sigmoidf_(zf), so = sigmoidf_(zo);
      float tg = tanhf_(zg);
      float cn = sf * cst[r] + si * tg;
      cst[r] = cn;
      hs[r] = f2bf(so * tanhf_(cn));
    }

    // publish h(t+1): LDS own-half (swizzled) + coherent global (partner + y_gemm)
    unsigned short* hw = h_hist + (size_t)(t + 1) * (BB * UU) + uloc;
#pragma unroll
    for (int r = 0; r < 4; ++r) {
      const int row = 4 * lhi + r;
      const int byte = nxt * 4096 + row * 256 + (((w * 16 + lr) * 2) ^ ((row & 7) << 4));
      *(unsigned short*)(hlds + byte) = hs[r];
      store_coh_u16(hw + (size_t)(b0 + row) * UU, hs[r]);
    }

    // drain h stores to the MALL before releasing the flag
    asm volatile("s_waitcnt vmcnt(0)" ::: "memory");
    __syncthreads();
    if (tid == 0)
      __hip_atomic_store(&flags[bid * 32], t + 1, __ATOMIC_RELAXED, __HIP_MEMORY_SCOPE_SYSTEM);
  }
}

template <typename XT>
__global__ void __launch_bounds__(512, 2)
lstm_main7(const XT* __restrict__ x, const unsigned short* __restrict__ Wt,
           const float* __restrict__ bvec, unsigned short* __restrict__ h_hist, int* flags) {
  __shared__ __align__(16) char lds[139264];  // 128KB Wx + 8KB h dbuf (+pad)
  const int bid = blockIdx.x;
  if (bid < 32) lstm_core<0, XT>(x, Wt, bvec, h_hist, flags, bid, lds);
  else          lstm_core<1, XT>(x, Wt, bvec, h_hist, flags, bid, lds);
}

// ---- y = h @ Wo + bo --------------------------------------------------------------------
__global__ void __launch_bounds__(256)
y_gemm(const unsigned short* __restrict__ h_hist, const unsigned short* __restrict__ Wot,
       const float* __restrict__ bo, float* __restrict__ out) {
  int gw = (int)((blockIdx.x * 256 + threadIdx.x) >> 6);
  int l = threadIdx.x & 63;
  int lr = l & 15, lhi = l >> 4;
  int b = gw >> 5;
  int t0 = (gw & 31) * 16;

  short8 Wf[2][8];
#pragma unroll
  for (int n = 0; n < 2; ++n) {
    const unsigned short* wp = Wot + (n * 16 + lr) * 256 + 8 * lhi;
#pragma unroll
    for (int kk = 0; kk < 8; ++kk) Wf[n][kk] = *(const short8*)(wp + kk * 32);
  }
  f32x4 acc[2];
#pragma unroll
  for (int n = 0; n < 2; ++n) {
    float bb = bo[n * 16 + lr];
    f32x4 a4 = {bb, bb, bb, bb};
    acc[n] = a4;
  }
  const unsigned short* hp =
      h_hist + ((size_t)(t0 + lr + 1) * BB + b) * UU + 8 * lhi;
#pragma unroll
  for (int kk = 0; kk < 8; ++kk) {
    short8 a = *(const short8*)(hp + kk * 32);
#pragma unroll
    for (int n = 0; n < 2; ++n)
      acc[n] = __builtin_amdgcn_mfma_f32_16x16x32_bf16(a, Wf[n][kk], acc[n], 0, 0, 0);
  }
#pragma unroll
  for (int n = 0; n < 2; ++n) {
    int o = n * 16 + lr;
#pragma unroll
    for (int r = 0; r < 4; ++r) {
      int t = t0 + 4 * lhi + r;
      out[((size_t)b * TT + t) * 32 + o] = acc[n][r];
    }
  }
}

extern "C" void kernel_launch(void* const* d_in, const int* in_sizes, int n_in,
                              void* d_out, int out_size, void* d_ws, size_t ws_size,
                              hipStream_t stream) {
  const float* x  = (const float*)d_in[0];
  const float* Wx = (const float*)d_in[1];
  const float* Wh = (const float*)d_in[2];
  const float* bv = (const float*)d_in[3];
  const float* Wo = (const float*)d_in[4];
  const float* bo = (const float*)d_in[5];

  char* ws = (char*)d_ws;
  size_t off = 0;
  unsigned short* h_hist = (unsigned short*)(ws + off); off += (size_t)513 * BB * UU * 2; // 134.5 MB
  unsigned short* Wt384  = (unsigned short*)(ws + off); off += (size_t)1024 * 384 * 2;
  unsigned short* Wot    = (unsigned short*)(ws + off); off += (size_t)32 * 256 * 2;
  int* flags             = (int*)(ws + off);            off += (size_t)64 * 32 * 4;
  off = (off + 255) & ~(size_t)255;
  unsigned short* xb = (unsigned short*)(ws + off);
  const size_t need_xb = off + (size_t)BB * TT * FF * 2;  // ~202 MB total

  prep_w<<<1026, 384, 0, stream>>>(Wx, Wh, Wo, Wt384, Wot, flags);
  if (ws_size >= need_xb) {
    conv_x<<<32768, 256, 0, stream>>>(x, xb);
    lstm_main7<unsigned short><<<64, 512, 0, stream>>>(xb, Wt384, bv, h_hist, flags);
  } else {
    lstm_main7<float><<<64, 512, 0, stream>>>(x, Wt384, bv, h_hist, flags);
  }
  y_gemm<<<4096, 256, 0, stream>>>(h_hist, Wot, bo, (float*)d_out);
}